// Round 1
// baseline (449.536 us; speedup 1.0000x reference)
//
#include <hip/hip_runtime.h>

// 3x3 median pool, stride 1, zero-pad 1, (8,32,512,512) fp32.
// One wave per (16-row x 256-col) strip: lane i owns 4 contiguous columns
// (float4 loads / nontemporal float4 stores, fully coalesced). All 18 input
// rows of the strip are loaded up-front for deep MLP. Wave-edge halo columns
// loaded by lanes 0/63 (1 dword each).
//
// RPS=16 (was 8): read amplification 18/16 = 1.125x (was 10/8 = 1.25x).
// XCD-chunk swizzle: consecutive hardware blockIdx round-robins across the
// 8 XCDs; remap so each XCD owns a contiguous 512-block chunk -> vertically
// adjacent strips re-read their 2 shared overlap rows out of the same XCD's
// L2 instead of HBM.
// Nontemporal stores: the 268 MB write-once output stream must not evict
// the input overlap lines from the 4 MB/XCD L2.

typedef float f32x4 __attribute__((ext_vector_type(4)));

#define S2(a, b) { float _t = fminf(a, b); b = fmaxf(a, b); a = _t; }

__device__ __forceinline__ float med3f(float a, float b, float c) {
    return fmaxf(fminf(a, b), fminf(fmaxf(a, b), c));
}
__device__ __forceinline__ float max3f(float a, float b, float c) {
    return fmaxf(fmaxf(a, b), c);
}
__device__ __forceinline__ float min3f(float a, float b, float c) {
    return fminf(fminf(a, b), c);
}

// launch_bounds(256, 3): ~115 VGPR expected; cap at 3 waves/EU budget (~168
// VGPR) so the 18-row register file never spills. Actual use <=128 still
// yields 4 waves/EU occupancy.
__global__ __launch_bounds__(256, 3) void median_pool3x3_kernel(
        const float* __restrict__ in, float* __restrict__ out) {
    constexpr int W = 512, H = 512;
    constexpr int RPS = 16;                // output rows per strip

    const int lane = threadIdx.x & 63;
    const int wib  = threadIdx.x >> 6;

    // 4096 blocks total; 8 XCDs -> 512-block contiguous chunk per XCD.
    // HW maps blockIdx.x b -> XCD (b & 7); logical id walks within the chunk.
    const int swz = (blockIdx.x & 7) * 512 + (blockIdx.x >> 3);
    const int gw  = swz * 4 + wib;

    // gw -> { img (256), strip (32), half (2) }; halves of one strip and the
    // two vertically adjacent strips share a block -> halo/overlap lines are
    // L1/L2-local.
    const int half  = gw & 1;
    const int strip = (gw >> 1) & 31;
    const int img   = gw >> 6;

    const int x0w = half * 256;
    const int y0  = strip * RPS;
    const float* __restrict__ base  = in  + (size_t)img * H * W;
    float* __restrict__       obase = out + (size_t)img * H * W;
    const int x0 = x0w + lane * 4;

    // Halo column config: lane 0 owns column x0w-1, lane 63 owns x0w+256.
    const bool isL = (lane == 0), isR = (lane == 63);
    const int  hx = isL ? (x0w - 1) : (x0w + 256);
    const bool hActive = (isL && x0w > 0) || (isR && x0w + 256 < W);

    // ---- load all 18 rows (y0-1 .. y0+16) up front: max loads in flight ----
    f32x4 r[RPS + 2];
    float h[RPS + 2];
    #pragma unroll
    for (int i = 0; i < RPS + 2; ++i) {
        const int y = y0 - 1 + i;
        h[i] = 0.0f;
        if (y >= 0 && y < H) {            // wave-uniform (strip edges only)
            r[i] = *(const f32x4*)(base + (size_t)y * W + x0);
            if (hActive) h[i] = base[(size_t)y * W + hx];
        } else {
            r[i] = (f32x4){0.0f, 0.0f, 0.0f, 0.0f};
        }
    }

    // ---- compute 16 output rows ----
    #pragma unroll
    for (int yy = 0; yy < RPS; ++yy) {
        const int y = y0 + yy;

        float av[4] = { r[yy].x,   r[yy].y,   r[yy].z,   r[yy].w   };
        float bv[4] = { r[yy+1].x, r[yy+1].y, r[yy+1].z, r[yy+1].w };
        float cv[4] = { r[yy+2].x, r[yy+2].y, r[yy+2].z, r[yy+2].w };

        float lo[4], mi[4], hi[4];
        #pragma unroll
        for (int j = 0; j < 4; ++j) {
            float a = av[j], b = bv[j], c = cv[j];
            S2(a, b); S2(b, c); S2(a, b);
            lo[j] = a; mi[j] = b; hi[j] = c;
        }

        // halo sorted triple (meaningful on lanes 0 and 63; zeros elsewhere)
        float ha = h[yy], hb = h[yy+1], hc = h[yy+2];
        S2(ha, hb); S2(hb, hc); S2(ha, hb);

        // neighbor sorted columns from adjacent lanes
        float loL = __shfl_up(lo[3], 1);
        float miL = __shfl_up(mi[3], 1);
        float hiL = __shfl_up(hi[3], 1);
        float loR = __shfl_down(lo[0], 1);
        float miR = __shfl_down(mi[0], 1);
        float hiR = __shfl_down(hi[0], 1);
        if (isL) { loL = ha; miL = hb; hiL = hc; }
        if (isR) { loR = ha; miR = hb; hiR = hc; }

        float o0 = med3f(max3f(loL,  lo[0], lo[1]),
                         med3f(miL,  mi[0], mi[1]),
                         min3f(hiL,  hi[0], hi[1]));
        float o1 = med3f(max3f(lo[0], lo[1], lo[2]),
                         med3f(mi[0], mi[1], mi[2]),
                         min3f(hi[0], hi[1], hi[2]));
        float o2 = med3f(max3f(lo[1], lo[2], lo[3]),
                         med3f(mi[1], mi[2], mi[3]),
                         min3f(hi[1], hi[2], hi[3]));
        float o3 = med3f(max3f(lo[2], lo[3], loR),
                         med3f(mi[2], mi[3], miR),
                         min3f(hi[2], hi[3], hiR));

        f32x4 o = { o0, o1, o2, o3 };
        __builtin_nontemporal_store(o, (f32x4*)(obase + (size_t)y * W + x0));
    }
}

extern "C" void kernel_launch(void* const* d_in, const int* in_sizes, int n_in,
                              void* d_out, int out_size, void* d_ws, size_t ws_size,
                              hipStream_t stream) {
    const float* x = (const float*)d_in[0];
    float* out = (float*)d_out;

    // 256 images x 32 strips x 2 halves = 16384 waves; 4 waves/block
    const int blocks = 16384 / 4;
    median_pool3x3_kernel<<<blocks, 256, 0, stream>>>(x, out);
}

// Round 2
// 440.610 us; speedup vs baseline: 1.0203x; 1.0203x over previous
//
#include <hip/hip_runtime.h>

// 3x3 median pool, stride 1, zero-pad 1, (8,32,512,512) fp32.
//
// Rolling-register streaming stencil: one wave owns a 64-row x 256-col block.
// Lane i owns 4 contiguous columns (float4 loads/stores, fully coalesced).
// An 8-slot register ring buffer walks down the rows: computing output row r
// consumes ring rows (r, r+1, r+2) and issues the load for row r+7, keeping
// 5 row-loads per wave continuously in flight (no load/compute phase
// bunching -- the round-1 kernel burst-loaded then burst-computed, leaving
// HBM idle half the time at 2.5 TB/s effective).
//
// Read amplification: 66 rows loaded / 64 rows produced = 1.03x.
// Grid: 256 planes x 2 col-halves x 2 row-quads = 1024 blocks x 4 waves
//     = 4096 waves = 4 blocks/CU exactly, all resident, no tail.
// Wave-edge halo columns loaded by lanes 0/63 (1 dword each), which then own
// the neighbor sorted triple; interior neighbors come via __shfl.

typedef float f32x4 __attribute__((ext_vector_type(4)));

#define S2(a, b) { float _t = fminf(a, b); b = fmaxf(a, b); a = _t; }

__device__ __forceinline__ float med3f(float a, float b, float c) {
    return fmaxf(fminf(a, b), fminf(fmaxf(a, b), c));
}
__device__ __forceinline__ float max3f(float a, float b, float c) {
    return fmaxf(fmaxf(a, b), c);
}
__device__ __forceinline__ float min3f(float a, float b, float c) {
    return fminf(fminf(a, b), c);
}

__global__ __launch_bounds__(256, 4) void median_pool3x3_kernel(
        const float* __restrict__ in, float* __restrict__ out) {
    constexpr int W = 512, H = 512;
    constexpr int RPW = 64;                // output rows per wave

    const int lane = threadIdx.x & 63;
    const int wib  = threadIdx.x >> 6;
    const int bid  = blockIdx.x;

    // bid -> { img (256), quad (2), half (2) }; wave wib takes row-block
    // quad*4+wib. Block therefore covers 256 rows x 256 cols of one plane.
    const int half = bid & 1;
    const int quad = (bid >> 1) & 1;
    const int img  = bid >> 2;
    const int y0   = (quad * 4 + wib) * RPW;

    const int x0w = half * 256;
    const int x0  = x0w + lane * 4;
    const float* __restrict__ base  = in  + (size_t)img * H * W;
    float* __restrict__       obase = out + (size_t)img * H * W;
    const float* __restrict__ pin   = base + x0;

    // Halo column: lane 0 owns column x0w-1, lane 63 owns x0w+256.
    const bool isL = (lane == 0), isR = (lane == 63);
    const int  hx = isL ? (x0w - 1) : (x0w + 256);
    const bool hActive = (isL && x0w > 0) || (isR && x0w + 256 < W);

    f32x4 r[8];                // ring: load k (input row y0-1+k) -> slot k&7
    float h[8];

    // ---- prologue: load k = 0..6 (rows y0-1 .. y0+5) ----
    #pragma unroll
    for (int k = 0; k < 7; ++k) {
        const int y = y0 - 1 + k;          // <= y0+5 <= 453, only k=0 can be <0
        if (y >= 0) {                      // wave-uniform
            r[k] = *(const f32x4*)(pin + (size_t)y * W);
            h[k] = hActive ? base[(size_t)y * W + hx] : 0.0f;
        } else {
            r[k] = (f32x4){0.0f, 0.0f, 0.0f, 0.0f};
            h[k] = 0.0f;
        }
    }

    // ---- one output row: consume ring slots sa,sb,sc; write row y ----
    auto crow = [&](const f32x4& A, const f32x4& B, const f32x4& C,
                    float hA, float hB, float hC, int y) {
        float lo[4], mi[4], hi[4];
        #pragma unroll
        for (int j = 0; j < 4; ++j) {
            float a = A[j], b = B[j], c = C[j];
            S2(a, b); S2(b, c); S2(a, b);
            lo[j] = a; mi[j] = b; hi[j] = c;
        }

        // halo sorted triple (meaningful on lanes 0 and 63)
        float ha = hA, hb = hB, hc = hC;
        S2(ha, hb); S2(hb, hc); S2(ha, hb);

        float loL = __shfl_up(lo[3], 1);
        float miL = __shfl_up(mi[3], 1);
        float hiL = __shfl_up(hi[3], 1);
        float loR = __shfl_down(lo[0], 1);
        float miR = __shfl_down(mi[0], 1);
        float hiR = __shfl_down(hi[0], 1);
        if (isL) { loL = ha; miL = hb; hiL = hc; }
        if (isR) { loR = ha; miR = hb; hiR = hc; }

        float o0 = med3f(max3f(loL,  lo[0], lo[1]),
                         med3f(miL,  mi[0], mi[1]),
                         min3f(hiL,  hi[0], hi[1]));
        float o1 = med3f(max3f(lo[0], lo[1], lo[2]),
                         med3f(mi[0], mi[1], mi[2]),
                         min3f(hi[0], hi[1], hi[2]));
        float o2 = med3f(max3f(lo[1], lo[2], lo[3]),
                         med3f(mi[1], mi[2], mi[3]),
                         min3f(hi[1], hi[2], hi[3]));
        float o3 = med3f(max3f(lo[2], lo[3], loR),
                         med3f(mi[2], mi[3], miR),
                         min3f(hi[2], hi[3], hiR));

        f32x4 o = { o0, o1, o2, o3 };
        *(f32x4*)(obase + (size_t)y * W + x0) = o;
    };

    // ---- 8-row body: rbase % 8 == 0, so slot indices are static after
    //      unroll (q, (q+1)&7, (q+2)&7; load into (q+7)&7). ----
    auto rows8 = [&](int rbase, bool tail) {
        #pragma unroll
        for (int q = 0; q < 8; ++q) {
            const int r_ = rbase + q;          // output row index 0..63
            const int sl = (q + 7) & 7;        // ring slot for load k=r_+7
            if (!tail) {
                // y = y0 + r_ + 6, always in [6, 509] here -> no check
                const int y = y0 + r_ + 6;
                r[sl] = *(const f32x4*)(pin + (size_t)y * W);
                h[sl] = hActive ? base[(size_t)y * W + hx] : 0.0f;
            } else if (q < 3) {
                // k = 63+q (q=0,1,2); only k=65 (row y0+64) can be invalid
                const int y = y0 + r_ + 6;
                if (y < H) {                   // wave-uniform
                    r[sl] = *(const f32x4*)(pin + (size_t)y * W);
                    h[sl] = hActive ? base[(size_t)y * W + hx] : 0.0f;
                } else {
                    r[sl] = (f32x4){0.0f, 0.0f, 0.0f, 0.0f};
                    h[sl] = 0.0f;
                }
            }
            crow(r[q], r[(q + 1) & 7], r[(q + 2) & 7],
                 h[q], h[(q + 1) & 7], h[(q + 2) & 7], y0 + r_);
        }
    };

    #pragma unroll 1
    for (int rb = 0; rb < 7; ++rb)
        rows8(rb * 8, false);
    rows8(56, true);
}

extern "C" void kernel_launch(void* const* d_in, const int* in_sizes, int n_in,
                              void* d_out, int out_size, void* d_ws, size_t ws_size,
                              hipStream_t stream) {
    const float* x = (const float*)d_in[0];
    float* out = (float*)d_out;

    // 256 planes x 2 halves x 2 quads = 1024 blocks, 4 waves each
    median_pool3x3_kernel<<<1024, 256, 0, stream>>>(x, out);
}